// Round 2
// baseline (1163.523 us; speedup 1.0000x reference)
//
#include <hip/hip_runtime.h>

typedef __bf16 bf16_t;
typedef __bf16 bf16x8 __attribute__((ext_vector_type(8)));
typedef float f32x4 __attribute__((ext_vector_type(4)));

#define N_NODES 50000
#define N_EDGES 400000
#define D_IN    256
#define D_HID   512
#define D_OUT   128
#define N_LAYERS 4

// ---------------- fp32 -> bf16 conversion ----------------

__global__ void f32_to_bf16(const float* __restrict__ in, bf16_t* __restrict__ out, int n) {
    int idx = (blockIdx.x * blockDim.x + threadIdx.x) * 4;
    if (idx + 3 < n) {
        float4 v = *reinterpret_cast<const float4*>(in + idx);
        bf16_t o[4] = {(bf16_t)v.x, (bf16_t)v.y, (bf16_t)v.z, (bf16_t)v.w};
        *reinterpret_cast<uint2*>(out + idx) = *reinterpret_cast<const uint2*>(o);
    } else {
        for (int j = idx; j < n; j++) out[j] = (bf16_t)in[j];
    }
}

// ---------------- degree / CSR build ----------------

__global__ void count_deg(const int* __restrict__ dst, int* __restrict__ deg, int E) {
    int e = blockIdx.x * blockDim.x + threadIdx.x;
    if (e < E) atomicAdd(&deg[dst[e]], 1);
}

__global__ void scan_reduce(const int* __restrict__ deg, int* __restrict__ partial, int N) {
    __shared__ int red[256];
    int base = blockIdx.x * 1024;
    int s = 0;
    for (int i = threadIdx.x; i < 1024; i += 256) {
        int idx = base + i;
        s += (idx < N) ? deg[idx] : 0;
    }
    red[threadIdx.x] = s;
    __syncthreads();
    for (int off = 128; off > 0; off >>= 1) {
        if (threadIdx.x < off) red[threadIdx.x] += red[threadIdx.x + off];
        __syncthreads();
    }
    if (threadIdx.x == 0) partial[blockIdx.x] = red[0];
}

__global__ void scan_partials(int* __restrict__ partial, int nb,
                              int* __restrict__ row_start, int N, int E) {
    if (threadIdx.x == 0 && blockIdx.x == 0) {
        int acc = 0;
        for (int i = 0; i < nb; i++) { int v = partial[i]; partial[i] = acc; acc += v; }
        row_start[N] = E;  // total in-degree == E
    }
}

__global__ void scan_chunks(const int* __restrict__ deg, const int* __restrict__ partial,
                            int* __restrict__ row_start, int N) {
    __shared__ int buf[2][1024];
    int t = threadIdx.x;
    int gid = blockIdx.x * 1024 + t;
    int v = (gid < N) ? deg[gid] : 0;
    int cur = 0;
    buf[0][t] = v;
    __syncthreads();
    for (int off = 1; off < 1024; off <<= 1) {
        int nxt = cur ^ 1;
        int val = buf[cur][t];
        if (t >= off) val += buf[cur][t - off];
        buf[nxt][t] = val;
        cur = nxt;
        __syncthreads();
    }
    int incl = buf[cur][t];
    if (gid < N) row_start[gid] = partial[blockIdx.x] + incl - v;  // exclusive
}

__global__ void compute_dinv(const int* __restrict__ deg, float* __restrict__ dinv, int N) {
    int n = blockIdx.x * blockDim.x + threadIdx.x;
    if (n < N) dinv[n] = rsqrtf((float)(deg[n] + 1));  // +1 self loop, always >= 1
}

__global__ void fill_csr(const int* __restrict__ ei, int E,
                         const int* __restrict__ row_start,
                         int* __restrict__ cursor, int* __restrict__ csr_src) {
    int e = blockIdx.x * blockDim.x + threadIdx.x;
    if (e < E) {
        int s = ei[e];
        int d = ei[E + e];
        int pos = atomicAdd(&cursor[d], 1);
        csr_src[row_start[d] + pos] = s;
    }
}

// ---------------- GEMM: C = act(A @ B + bias), bf16 in, fp32 accum ----------------
// A: [M,K] row-major bf16; B: [K,N] row-major bf16; bias fp32; C bf16 or fp32.
// 64x64 block tile, 4 waves of 32x32 (2x2 MFMA 16x16x32 tiles), LDS-staged.

template <bool F32OUT, bool RELU>
__global__ __launch_bounds__(256) void gemm_bias_act(
    const bf16_t* __restrict__ A, const bf16_t* __restrict__ B,
    const float* __restrict__ bias, void* __restrict__ Cv,
    int M, int N, int K)
{
    __shared__ __align__(16) bf16_t sA[64][40];   // +8 pad
    __shared__ __align__(16) bf16_t sBT[64][40];  // B transposed: [n][k]

    const int bn = blockIdx.x * 64;
    const int bm = blockIdx.y * 64;
    const int tid = threadIdx.x;
    const int lane = tid & 63;
    const int wave = tid >> 6;
    const int wm = (wave & 1) * 32;
    const int wn = (wave >> 1) * 32;
    const int lm = lane & 15;
    const int lq = lane >> 4;

    f32x4 acc[2][2] = {};

    // staging assignments
    const int ar = tid >> 2;          // 0..63 (A row)
    const int ac = (tid & 3) * 8;     // 0,8,16,24 (A col group)
    const int bk = tid >> 3;          // 0..31 (B k row)
    const int bng = (tid & 7) * 8;    // 0..56 (B n group)
    const int arow = bm + ar;
    const bool a_valid = (arow < M);

    const int nkb = K >> 5;
    for (int kb = 0; kb < nkb; kb++) {
        const int k0 = kb * 32;
        // stage A tile
        if (a_valid) {
            uint4 u = *reinterpret_cast<const uint4*>(A + (size_t)arow * K + k0 + ac);
            *reinterpret_cast<uint4*>(&sA[ar][ac]) = u;
        } else {
            uint4 z = make_uint4(0, 0, 0, 0);
            *reinterpret_cast<uint4*>(&sA[ar][ac]) = z;
        }
        // stage B tile transposed
        {
            uint4 u = *reinterpret_cast<const uint4*>(B + (size_t)(k0 + bk) * N + bn + bng);
            const bf16_t* bv = reinterpret_cast<const bf16_t*>(&u);
#pragma unroll
            for (int j = 0; j < 8; j++) sBT[bng + j][bk] = bv[j];
        }
        __syncthreads();

        bf16x8 a0 = *reinterpret_cast<bf16x8*>(&sA[wm + lm][lq * 8]);
        bf16x8 a1 = *reinterpret_cast<bf16x8*>(&sA[wm + 16 + lm][lq * 8]);
        bf16x8 b0 = *reinterpret_cast<bf16x8*>(&sBT[wn + lm][lq * 8]);
        bf16x8 b1 = *reinterpret_cast<bf16x8*>(&sBT[wn + 16 + lm][lq * 8]);

        acc[0][0] = __builtin_amdgcn_mfma_f32_16x16x32_bf16(a0, b0, acc[0][0], 0, 0, 0);
        acc[0][1] = __builtin_amdgcn_mfma_f32_16x16x32_bf16(a0, b1, acc[0][1], 0, 0, 0);
        acc[1][0] = __builtin_amdgcn_mfma_f32_16x16x32_bf16(a1, b0, acc[1][0], 0, 0, 0);
        acc[1][1] = __builtin_amdgcn_mfma_f32_16x16x32_bf16(a1, b1, acc[1][1], 0, 0, 0);
        __syncthreads();
    }

    // epilogue: C/D layout col=lane&15, row=lq*4+reg
#pragma unroll
    for (int nt = 0; nt < 2; nt++) {
        const int col = bn + wn + nt * 16 + lm;
        const float bv = bias ? bias[col] : 0.0f;
#pragma unroll
        for (int mt = 0; mt < 2; mt++) {
#pragma unroll
            for (int r = 0; r < 4; r++) {
                const int row = bm + wm + mt * 16 + lq * 4 + r;
                if (row < M) {
                    float v = acc[mt][nt][r] + bv;
                    if (RELU) v = fmaxf(v, 0.0f);
                    if (F32OUT) {
                        ((float*)Cv)[(size_t)row * N + col] = v;
                    } else {
                        ((bf16_t*)Cv)[(size_t)row * N + col] = (bf16_t)v;
                    }
                }
            }
        }
    }
}

// ---------------- aggregation ----------------
// h_out[n] = sum_{s->n} dinv[s]*dinv[n]*hw[s] + dinv[n]^2*hw[n] + bias
// one wave per node; lane handles 8 contiguous features (D_HID=512 = 64 lanes * 8)

__global__ __launch_bounds__(256) void aggregate(
    const bf16_t* __restrict__ hw, const float* __restrict__ dinv,
    const int* __restrict__ row_start, const int* __restrict__ csr_src,
    const float* __restrict__ bias, bf16_t* __restrict__ h_out, int N)
{
    const int n = blockIdx.x * 4 + (threadIdx.x >> 6);
    const int lane = threadIdx.x & 63;
    if (n >= N) return;

    const float dn = dinv[n];
    const int f = lane * 8;
    float acc[8];

    // self loop: norm = dinv[n]^2
    {
        uint4 u = *reinterpret_cast<const uint4*>(hw + (size_t)n * D_HID + f);
        const unsigned short* hv = reinterpret_cast<const unsigned short*>(&u);
        const float nm = dn * dn;
#pragma unroll
        for (int j = 0; j < 8; j++) {
            acc[j] = nm * __uint_as_float(((unsigned int)hv[j]) << 16);
        }
    }

    const int beg = row_start[n];
    const int end = row_start[n + 1];
    for (int p = beg; p < end; p++) {
        const int s = csr_src[p];
        const float nm = dinv[s] * dn;
        uint4 u = *reinterpret_cast<const uint4*>(hw + (size_t)s * D_HID + f);
        const unsigned short* hv = reinterpret_cast<const unsigned short*>(&u);
#pragma unroll
        for (int j = 0; j < 8; j++) {
            acc[j] = fmaf(nm, __uint_as_float(((unsigned int)hv[j]) << 16), acc[j]);
        }
    }

    bf16_t outv[8];
#pragma unroll
    for (int j = 0; j < 8; j++) outv[j] = (bf16_t)(acc[j] + bias[f + j]);
    *reinterpret_cast<uint4*>(h_out + (size_t)n * D_HID + f) = *reinterpret_cast<const uint4*>(outv);
}

// ---------------- orchestration ----------------

extern "C" void kernel_launch(void* const* d_in, const int* in_sizes, int n_in,
                              void* d_out, int out_size, void* d_ws, size_t ws_size,
                              hipStream_t stream) {
    const int N = N_NODES, E = N_EDGES;

    const float* x  = (const float*)d_in[0];
    const int*   ei = (const int*)d_in[1];
    const float* W1 = (const float*)d_in[2];
    const float* b1 = (const float*)d_in[3];
    const float* Wc = (const float*)d_in[4];
    const float* bc = (const float*)d_in[5];
    const float* W2 = (const float*)d_in[6];
    const float* b2 = (const float*)d_in[7];
    float* out = (float*)d_out;

    char* ws = (char*)d_ws;
    size_t off = 0;
    auto alloc = [&](size_t bytes) -> void* {
        void* p = ws + off;
        off += (bytes + 255) & ~(size_t)255;
        return p;
    };
    int*    deg       = (int*)alloc((size_t)N * 4);
    int*    cursor    = (int*)alloc((size_t)N * 4);
    int*    row_start = (int*)alloc((size_t)(N + 1) * 4);
    int*    partial   = (int*)alloc(256 * 4);
    float*  dinv      = (float*)alloc((size_t)N * 4);
    int*    csr_src   = (int*)alloc((size_t)E * 4);
    bf16_t* h         = (bf16_t*)alloc((size_t)N * D_HID * 2);
    bf16_t* hw        = (bf16_t*)alloc((size_t)N * D_HID * 2);
    bf16_t* xb        = (bf16_t*)alloc((size_t)N * D_IN * 2);
    bf16_t* W1b       = (bf16_t*)alloc((size_t)D_IN * D_HID * 2);
    bf16_t* Wcb       = (bf16_t*)alloc((size_t)N_LAYERS * D_HID * D_HID * 2);
    bf16_t* W2b       = (bf16_t*)alloc((size_t)D_HID * D_OUT * 2);

    hipMemsetAsync(deg, 0, (size_t)N * 4, stream);
    hipMemsetAsync(cursor, 0, (size_t)N * 4, stream);

    // fp32 -> bf16 weight / input conversion
    {
        int n;
        n = N * D_IN;                    f32_to_bf16<<<(n / 4 + 255) / 256, 256, 0, stream>>>(x,  xb,  n);
        n = D_IN * D_HID;                f32_to_bf16<<<(n / 4 + 255) / 256, 256, 0, stream>>>(W1, W1b, n);
        n = N_LAYERS * D_HID * D_HID;    f32_to_bf16<<<(n / 4 + 255) / 256, 256, 0, stream>>>(Wc, Wcb, n);
        n = D_HID * D_OUT;               f32_to_bf16<<<(n / 4 + 255) / 256, 256, 0, stream>>>(W2, W2b, n);
    }

    // CSR build (same graph every layer; rebuilt each call since ws is re-poisoned)
    count_deg<<<(E + 255) / 256, 256, 0, stream>>>(ei + E, deg, E);
    const int nch = (N + 1023) / 1024;  // 49
    scan_reduce<<<nch, 256, 0, stream>>>(deg, partial, N);
    scan_partials<<<1, 64, 0, stream>>>(partial, nch, row_start, N, E);
    scan_chunks<<<nch, 1024, 0, stream>>>(deg, partial, row_start, N);
    compute_dinv<<<(N + 255) / 256, 256, 0, stream>>>(deg, dinv, N);
    fill_csr<<<(E + 255) / 256, 256, 0, stream>>>(ei, E, row_start, cursor, csr_src);

    const dim3 blk(256);
    const dim3 g_mid(D_HID / 64, (N + 63) / 64);

    // dnn1: h = relu(x @ W1 + b1)
    gemm_bias_act<false, true><<<g_mid, blk, 0, stream>>>(xb, W1b, b1, h, N, D_HID, D_IN);

    // GCN layers
    for (int i = 0; i < N_LAYERS; i++) {
        gemm_bias_act<false, false><<<g_mid, blk, 0, stream>>>(
            h, Wcb + (size_t)i * D_HID * D_HID, nullptr, hw, N, D_HID, D_HID);
        aggregate<<<(N + 3) / 4, 256, 0, stream>>>(hw, dinv, row_start, csr_src,
                                                   bc + (size_t)i * D_HID, h, N);
    }

    // dnn2: out = h @ W2 + b2
    gemm_bias_act<true, false><<<dim3(D_OUT / 64, (N + 63) / 64), blk, 0, stream>>>(
        h, W2b, b2, out, N, D_OUT, D_HID);
}

// Round 3
// 878.808 us; speedup vs baseline: 1.3240x; 1.3240x over previous
//
#include <hip/hip_runtime.h>

typedef __bf16 bf16_t;
typedef __bf16 bf16x8 __attribute__((ext_vector_type(8)));
typedef float f32x4 __attribute__((ext_vector_type(4)));

#define N_NODES 50000
#define N_PAD   50048   // padded to multiple of 128 for 128-row GEMM tiles
#define N_EDGES 400000
#define D_IN    256
#define D_HID   512
#define D_OUT   128
#define N_LAYERS 4

#define AS1 __attribute__((address_space(1)))
#define AS3 __attribute__((address_space(3)))

// ---------------- fp32 -> bf16 conversion (flat, for x) ----------------

__global__ void f32_to_bf16(const float* __restrict__ in, bf16_t* __restrict__ out, int n) {
    int idx = (blockIdx.x * blockDim.x + threadIdx.x) * 4;
    if (idx + 3 < n) {
        float4 v = *reinterpret_cast<const float4*>(in + idx);
        bf16_t o[4] = {(bf16_t)v.x, (bf16_t)v.y, (bf16_t)v.z, (bf16_t)v.w};
        *reinterpret_cast<uint2*>(out + idx) = *reinterpret_cast<const uint2*>(o);
    } else {
        for (int j = idx; j < n; j++) out[j] = (bf16_t)in[j];
    }
}

// ---------------- fp32 [R][C] -> bf16 transposed [C][R] (for weights) ----------------
// R, C multiples of 32. block (32,8), 32x32 LDS tile.

__global__ void transpose_to_bf16(const float* __restrict__ in, bf16_t* __restrict__ out,
                                  int R, int C) {
    __shared__ float tile[32][33];
    const int c0 = blockIdx.x * 32;
    const int r0 = blockIdx.y * 32;
    for (int i = threadIdx.y; i < 32; i += 8)
        tile[i][threadIdx.x] = in[(size_t)(r0 + i) * C + c0 + threadIdx.x];
    __syncthreads();
    for (int i = threadIdx.y; i < 32; i += 8)
        out[(size_t)(c0 + i) * R + r0 + threadIdx.x] = (bf16_t)tile[threadIdx.x][i];
}

// ---------------- degree / CSR build ----------------

__global__ void count_deg(const int* __restrict__ dst, int* __restrict__ deg, int E) {
    int e = blockIdx.x * blockDim.x + threadIdx.x;
    if (e < E) atomicAdd(&deg[dst[e]], 1);
}

__global__ void scan_reduce(const int* __restrict__ deg, int* __restrict__ partial, int N) {
    __shared__ int red[256];
    int base = blockIdx.x * 1024;
    int s = 0;
    for (int i = threadIdx.x; i < 1024; i += 256) {
        int idx = base + i;
        s += (idx < N) ? deg[idx] : 0;
    }
    red[threadIdx.x] = s;
    __syncthreads();
    for (int off = 128; off > 0; off >>= 1) {
        if (threadIdx.x < off) red[threadIdx.x] += red[threadIdx.x + off];
        __syncthreads();
    }
    if (threadIdx.x == 0) partial[blockIdx.x] = red[0];
}

__global__ void scan_partials(int* __restrict__ partial, int nb,
                              int* __restrict__ row_start, int N, int E) {
    if (threadIdx.x == 0 && blockIdx.x == 0) {
        int acc = 0;
        for (int i = 0; i < nb; i++) { int v = partial[i]; partial[i] = acc; acc += v; }
        row_start[N] = E;
    }
}

__global__ void scan_chunks(const int* __restrict__ deg, const int* __restrict__ partial,
                            int* __restrict__ row_start, int N) {
    __shared__ int buf[2][1024];
    int t = threadIdx.x;
    int gid = blockIdx.x * 1024 + t;
    int v = (gid < N) ? deg[gid] : 0;
    int cur = 0;
    buf[0][t] = v;
    __syncthreads();
    for (int off = 1; off < 1024; off <<= 1) {
        int nxt = cur ^ 1;
        int val = buf[cur][t];
        if (t >= off) val += buf[cur][t - off];
        buf[nxt][t] = val;
        cur = nxt;
        __syncthreads();
    }
    int incl = buf[cur][t];
    if (gid < N) row_start[gid] = partial[blockIdx.x] + incl - v;  // exclusive
}

__global__ void compute_dinv(const int* __restrict__ deg, float* __restrict__ dinv, int N) {
    int n = blockIdx.x * blockDim.x + threadIdx.x;
    if (n < N) dinv[n] = rsqrtf((float)(deg[n] + 1));  // +1 self loop
}

__global__ void fill_csr(const int* __restrict__ ei, int E,
                         const int* __restrict__ row_start,
                         int* __restrict__ cursor, int* __restrict__ csr_src) {
    int e = blockIdx.x * blockDim.x + threadIdx.x;
    if (e < E) {
        int s = ei[e];
        int d = ei[E + e];
        int pos = atomicAdd(&cursor[d], 1);
        csr_src[row_start[d] + pos] = s;
    }
}

// ---------------- GEMM (m97 structure): C = act(A @ BT^T + bias) ----------------
// A: [M_pad][K] bf16 row-major. BT: [N][K] bf16 row-major (pre-transposed weights).
// 128x128 block tile, 4 waves each 64x64 (4x4 MFMA 16x16x32), BK=32,
// global_load_lds width=16 staging (LDS layout [row][32], unpadded, lane-contiguous).

template <bool F32OUT, bool RELU>
__global__ __launch_bounds__(256) void gemm128(
    const bf16_t* __restrict__ A, const bf16_t* __restrict__ BT,
    const float* __restrict__ bias, void* __restrict__ Cv,
    int M, int N, int K)
{
    __shared__ __align__(16) bf16_t sA[128 * 32];
    __shared__ __align__(16) bf16_t sB[128 * 32];

    const int tid  = threadIdx.x;
    const int lane = tid & 63;
    const int wave = tid >> 6;
    const int bn = blockIdx.x * 128;
    const int bm = blockIdx.y * 128;
    const int wm = (wave & 1) * 64;
    const int wn = (wave >> 1) * 64;
    const int lm = lane & 15;
    const int lq = lane >> 4;

    // staging lane assignment: 16-row group per wave-load; 4 lanes per row (16B each)
    const int r4 = lane >> 2;          // row within 16-row group
    const int kq = (lane & 3) * 8;     // k offset (elements)

    f32x4 acc[4][4] = {};

    const int nkb = K >> 5;
    for (int kb = 0; kb < nkb; kb++) {
        const int k0 = kb * 32;
#pragma unroll
        for (int r = 0; r < 2; r++) {
            const int g = r * 4 + wave;              // 16-row group 0..7
            const int row = g * 16 + r4;
            __builtin_amdgcn_global_load_lds(
                (const AS1 unsigned int*)(A + (size_t)(bm + row) * K + k0 + kq),
                (AS3 unsigned int*)((AS3 char*)(AS3 bf16_t*)sA + g * 1024),
                16, 0, 0);
            __builtin_amdgcn_global_load_lds(
                (const AS1 unsigned int*)(BT + (size_t)(bn + row) * K + k0 + kq),
                (AS3 unsigned int*)((AS3 char*)(AS3 bf16_t*)sB + g * 1024),
                16, 0, 0);
        }
        __syncthreads();

        bf16x8 af[4], bf[4];
#pragma unroll
        for (int mt = 0; mt < 4; mt++)
            af[mt] = *reinterpret_cast<bf16x8*>(&sA[(wm + mt * 16 + lm) * 32 + lq * 8]);
#pragma unroll
        for (int nt = 0; nt < 4; nt++)
            bf[nt] = *reinterpret_cast<bf16x8*>(&sB[(wn + nt * 16 + lm) * 32 + lq * 8]);
#pragma unroll
        for (int mt = 0; mt < 4; mt++)
#pragma unroll
            for (int nt = 0; nt < 4; nt++)
                acc[mt][nt] = __builtin_amdgcn_mfma_f32_16x16x32_bf16(af[mt], bf[nt], acc[mt][nt], 0, 0, 0);
        __syncthreads();
    }

    // epilogue: C/D layout col=lane&15, row=lq*4+reg
#pragma unroll
    for (int nt = 0; nt < 4; nt++) {
        const int col = bn + wn + nt * 16 + lm;
        const float bv = bias ? bias[col] : 0.0f;
#pragma unroll
        for (int mt = 0; mt < 4; mt++) {
#pragma unroll
            for (int r = 0; r < 4; r++) {
                const int row = bm + wm + mt * 16 + lq * 4 + r;
                if (row < M) {
                    float v = acc[mt][nt][r] + bv;
                    if (RELU) v = fmaxf(v, 0.0f);
                    if (F32OUT) ((float*)Cv)[(size_t)row * N + col] = v;
                    else        ((bf16_t*)Cv)[(size_t)row * N + col] = (bf16_t)v;
                }
            }
        }
    }
}

// ---------------- aggregation ----------------
// h_out[n] = sum_{s->n} dinv[s]*dinv[n]*hw[s] + dinv[n]^2*hw[n] + bias
// one wave per node; lane handles 8 contiguous features (512 = 64*8)

__global__ __launch_bounds__(256) void aggregate(
    const bf16_t* __restrict__ hw, const float* __restrict__ dinv,
    const int* __restrict__ row_start, const int* __restrict__ csr_src,
    const float* __restrict__ bias, bf16_t* __restrict__ h_out, int N)
{
    const int n = blockIdx.x * 4 + (threadIdx.x >> 6);
    const int lane = threadIdx.x & 63;
    if (n >= N) return;

    const float dn = dinv[n];
    const int f = lane * 8;
    float acc[8];

    {   // self loop: norm = dinv[n]^2
        uint4 u = *reinterpret_cast<const uint4*>(hw + (size_t)n * D_HID + f);
        const unsigned short* hv = reinterpret_cast<const unsigned short*>(&u);
        const float nm = dn * dn;
#pragma unroll
        for (int j = 0; j < 8; j++)
            acc[j] = nm * __uint_as_float(((unsigned int)hv[j]) << 16);
    }

    const int beg = row_start[n];
    const int end = row_start[n + 1];
    for (int p = beg; p < end; p++) {
        const int s = csr_src[p];
        const float nm = dinv[s] * dn;
        uint4 u = *reinterpret_cast<const uint4*>(hw + (size_t)s * D_HID + f);
        const unsigned short* hv = reinterpret_cast<const unsigned short*>(&u);
#pragma unroll
        for (int j = 0; j < 8; j++)
            acc[j] = fmaf(nm, __uint_as_float(((unsigned int)hv[j]) << 16), acc[j]);
    }

    bf16_t outv[8];
#pragma unroll
    for (int j = 0; j < 8; j++) outv[j] = (bf16_t)(acc[j] + bias[f + j]);
    *reinterpret_cast<uint4*>(h_out + (size_t)n * D_HID + f) = *reinterpret_cast<const uint4*>(outv);
}

// ---------------- orchestration ----------------

extern "C" void kernel_launch(void* const* d_in, const int* in_sizes, int n_in,
                              void* d_out, int out_size, void* d_ws, size_t ws_size,
                              hipStream_t stream) {
    const int N = N_NODES, E = N_EDGES;

    const float* x  = (const float*)d_in[0];
    const int*   ei = (const int*)d_in[1];
    const float* W1 = (const float*)d_in[2];
    const float* b1 = (const float*)d_in[3];
    const float* Wc = (const float*)d_in[4];
    const float* bc = (const float*)d_in[5];
    const float* W2 = (const float*)d_in[6];
    const float* b2 = (const float*)d_in[7];
    float* out = (float*)d_out;

    char* ws = (char*)d_ws;
    size_t off = 0;
    auto alloc = [&](size_t bytes) -> void* {
        void* p = ws + off;
        off += (bytes + 255) & ~(size_t)255;
        return p;
    };
    int*    deg       = (int*)alloc((size_t)N * 4);
    int*    cursor    = (int*)alloc((size_t)N * 4);
    int*    row_start = (int*)alloc((size_t)(N + 1) * 4);
    int*    partial   = (int*)alloc(256 * 4);
    float*  dinv      = (float*)alloc((size_t)N * 4);
    int*    csr_src   = (int*)alloc((size_t)E * 4);
    bf16_t* h         = (bf16_t*)alloc((size_t)N_PAD * D_HID * 2);  // padded rows
    bf16_t* hw        = (bf16_t*)alloc((size_t)N_PAD * D_HID * 2);
    bf16_t* xb        = (bf16_t*)alloc((size_t)N_PAD * D_IN * 2);
    bf16_t* W1t       = (bf16_t*)alloc((size_t)D_HID * D_IN * 2);               // [512][256]
    bf16_t* Wct       = (bf16_t*)alloc((size_t)N_LAYERS * D_HID * D_HID * 2);   // [L][512][512]
    bf16_t* W2t       = (bf16_t*)alloc((size_t)D_OUT * D_HID * 2);              // [128][512]

    hipMemsetAsync(deg, 0, (size_t)N * 4, stream);
    hipMemsetAsync(cursor, 0, (size_t)N * 4, stream);

    // conversions: x flat; weights transposed to [N][K]
    {
        int n = N * D_IN;
        f32_to_bf16<<<(n / 4 + 255) / 256, 256, 0, stream>>>(x, xb, n);
        dim3 tb(32, 8);
        transpose_to_bf16<<<dim3(D_HID / 32, D_IN / 32), tb, 0, stream>>>(W1, W1t, D_IN, D_HID);
        for (int i = 0; i < N_LAYERS; i++)
            transpose_to_bf16<<<dim3(D_HID / 32, D_HID / 32), tb, 0, stream>>>(
                Wc + (size_t)i * D_HID * D_HID, Wct + (size_t)i * D_HID * D_HID, D_HID, D_HID);
        transpose_to_bf16<<<dim3(D_OUT / 32, D_HID / 32), tb, 0, stream>>>(W2, W2t, D_HID, D_OUT);
    }

    // CSR build
    count_deg<<<(E + 255) / 256, 256, 0, stream>>>(ei + E, deg, E);
    const int nch = (N + 1023) / 1024;
    scan_reduce<<<nch, 256, 0, stream>>>(deg, partial, N);
    scan_partials<<<1, 64, 0, stream>>>(partial, nch, row_start, N, E);
    scan_chunks<<<nch, 1024, 0, stream>>>(deg, partial, row_start, N);
    compute_dinv<<<(N + 255) / 256, 256, 0, stream>>>(deg, dinv, N);
    fill_csr<<<(E + 255) / 256, 256, 0, stream>>>(ei, E, row_start, cursor, csr_src);

    const dim3 blk(256);
    const int mg = N_PAD / 128;  // 391

    // dnn1: h = relu(x @ W1 + b1)
    gemm128<false, true><<<dim3(D_HID / 128, mg), blk, 0, stream>>>(xb, W1t, b1, h, N, D_HID, D_IN);

    // GCN layers
    for (int i = 0; i < N_LAYERS; i++) {
        gemm128<false, false><<<dim3(D_HID / 128, mg), blk, 0, stream>>>(
            h, Wct + (size_t)i * D_HID * D_HID, nullptr, hw, N, D_HID, D_HID);
        aggregate<<<(N + 3) / 4, 256, 0, stream>>>(hw, dinv, row_start, csr_src,
                                                   bc + (size_t)i * D_HID, h, N);
    }

    // dnn2: out = h @ W2 + b2 (fp32 out)
    gemm128<true, false><<<dim3(D_OUT / 128, mg), blk, 0, stream>>>(h, W2t, b2, out, N, D_OUT, D_HID);
}